// Round 1
// baseline (189.449 us; speedup 1.0000x reference)
//
#include <hip/hip_runtime.h>
#include <math.h>

// ImpulseSolverLCP — round 7: single fused kernel (W-precompute folded in).
//
// Math (identical to rounds 1-6, all PASSING):
//   K = [[pM+eI, G^T],[G, -F+eI]], pM = kron(M, I2), M = Minv^-1.
//   (pM+eI)^-1 = kron(W, I2), W = (I + e*Minv)^-1 Minv  (batch-shared).
//   Pair/row elimination leaves a symmetric 64x64 system in (lambda, delta);
//   4-wave distributed Gauss-Jordan, 16 phases x 4 pivots (round-6 structure,
//   numerically untouched here — same op order, same absmax ~0.0244).
//
// Round-7 change (why): rocprof top-5 = harness poison fills (2x 268 MB @
// ~6.7 TB/s ~= 80.5 us of the 93.2 us). Our kernels are ~13 us, and ~4-5 us
// of that is the second dispatch: precompute_W's launch node + the implicit
// grid-wide drain before solve_batch may start. Fix: fuse.
//  * Blocks 0..63, wave 0: compute one Neumann column of W (bitwise-identical
//    fma order to round-6 precompute_W), store to d_ws, agent-scope RELEASE
//    flag[col] = WMAGIC.
//  * All blocks: do W-independent work first (vw store, contact geometry),
//    then spin on the 64 flags (agent-scope ACQUIRE) — overlaps producer
//    latency — then stage Wl from global and proceed unchanged.
//  * No deadlock possible: producers depend on no other block; grid = 1024 =
//    4 blocks/CU residency capacity anyway. Bounded-spin fallback (computes
//    W locally per-block, same bits) is never-taken insurance.
//  * Flags live in poisoned workspace: first run spins correctly; if the
//    harness ever leaves stale WMAGIC across replays, the fast-pass reads
//    iteration-1's W which is bitwise identical (same Minv) — benign.

#define NBODY 64
#define NC    32
#define ND    128
#define EPS   1e-3f
#define WPAD  65
#define WMAGIC 0x1B7D3C5Au

__device__ __forceinline__ float readlane_f(float x, int lane) {
  return __int_as_float(__builtin_amdgcn_readlane(__float_as_int(x), lane));
}

__device__ __forceinline__ float rcp_fast(float x) {
  float r;
  asm("v_rcp_f32 %0, %1" : "=v"(r) : "v"(x));
  return r;
}

// One column of W = (I + eps*Minv)^-1 * Minv via 6 Neumann iterations + final
// matvec. Accumulation order matches round-6 precompute_W exactly (a0..a3
// partial sums by e%4, s = dlt - EPS*((a0+a1)+(a2+a3))) -> bitwise-equal W.
// t-loop kept rolled (#pragma unroll 1) so the 16 float4 Minv-row loads are
// not hoisted into 64 live VGPRs (we must stay <=128 for 4 blocks/CU).
__device__ __forceinline__ float neumann_col(const float* __restrict__ Minv,
                                             int lane, int col) {
  const float4* mv = (const float4*)(Minv + lane * NBODY);
  const float dlt = (lane == col) ? 1.0f : 0.0f;
  float s = dlt;
#pragma unroll 1
  for (int t = 0; t < 7; ++t) {
    float a0 = 0.f, a1 = 0.f, a2 = 0.f, a3 = 0.f;
#pragma unroll
    for (int e4 = 0; e4 < 16; ++e4) {
      float4 m = mv[e4];
      a0 = fmaf(m.x, readlane_f(s, 4 * e4),     a0);
      a1 = fmaf(m.y, readlane_f(s, 4 * e4 + 1), a1);
      a2 = fmaf(m.z, readlane_f(s, 4 * e4 + 2), a2);
      a3 = fmaf(m.w, readlane_f(s, 4 * e4 + 3), a3);
    }
    float acc = (a0 + a1) + (a2 + a3);
    s = (t < 6) ? (dlt - EPS * acc) : acc;
  }
  return s;
}

// ---------------- Fused kernel: W-produce + 4-wave Gauss-Jordan solve -------
__global__ __launch_bounds__(256, 4) void solve_batch_fused(
    const float* __restrict__ x, const float* __restrict__ v,
    const int* __restrict__ cld, const float* __restrict__ dist,
    const float* __restrict__ cor, const float* __restrict__ Minv,
    float* __restrict__ Wg, unsigned* __restrict__ flags,
    float* __restrict__ out) {
  __shared__ float Wl[NBODY * WPAD];
  __shared__ float vw[ND], qw[ND], yw[ND];
  __shared__ float4 mrow[2][64];     // [phase parity][lane] = (m0,m1,m2,m3)
  __shared__ float dv[64];           // pivot reciprocals

  const int tid  = threadIdx.x;
  const int w    = tid >> 6;         // wave id 0..3 (uniform per wave)
  const int lane = tid & 63;
  const int b    = blockIdx.x;

  // ---- producer: blocks 0..63, wave 0 compute W column b ------------------
  if (b < NBODY && w == 0) {
    float wcol = neumann_col(Minv, lane, b);
    Wg[lane * NBODY + b] = wcol;     // one wave-wide store instruction
    if (lane == 0)                   // release orders the wave's store above
      __hip_atomic_store(&flags[b], WMAGIC, __ATOMIC_RELEASE,
                         __HIP_MEMORY_SCOPE_AGENT);
  }

  // ---- consumer early work (no W dependency; overlaps producers) ----------
  const float* xb = x + b * ND;
  const float* vb = v + b * ND;

  const int half = w & 1;
  const int t = lane + 64 * half;    // output component (waves 0,1)
  if (w < 2) vw[t] = vb[t];

  // per-lane contact/row data (identical in all 4 waves)
  const int rc = lane & 31;
  const int myi = cld[b * 2 * NC + 2 * rc];
  const int myj = cld[b * 2 * NC + 2 * rc + 1];
  float dx = xb[2 * myj]     - xb[2 * myi];
  float dy = xb[2 * myj + 1] - xb[2 * myi + 1];
  float il = 1.0f / sqrtf(dx * dx + dy * dy);
  float enx = dx * il, eny = dy * il;
  float wx = (lane < 32) ? enx : -eny;   // row weight vector (en or et)
  float wy = (lane < 32) ? eny : enx;

  // ---- wait for all 64 W columns, then stage W into LDS -------------------
  {
    bool ready;
    int tries = 0;
    do {
      unsigned f = __hip_atomic_load(&flags[lane], __ATOMIC_ACQUIRE,
                                     __HIP_MEMORY_SCOPE_AGENT);
      ready = (bool)__all(f == WMAGIC);
      if (!ready) __builtin_amdgcn_s_sleep(2);
    } while (!ready && ++tries < (1 << 22));
    if (ready) {
      for (int idx = tid; idx < NBODY * NBODY; idx += 256)
        Wl[(idx >> 6) * WPAD + (idx & 63)] = Wg[idx];
    } else {
      // starvation fallback (never expected to execute): compute W locally.
      // Same fma order as producer -> bitwise-identical values; even if some
      // waves raced past via flags, duplicate Wl writes carry equal bits.
      for (int q = 0; q < 16; ++q) {
        int col = 16 * w + q;
        Wl[lane * WPAD + col] = neumann_col(Minv, lane, col);
      }
    }
  }

  __syncthreads();                       // #1: Wl + vw visible

  const int kc = lane & 1;
  const int a  = t >> 1;
  const float* Wa = Wl + a * WPAD;
  if (w < 2) {                           // q = v - eps*kron(W,I2) v, half each
    float s = 0.f;
    for (int e = 0; e < NBODY; ++e) s = fmaf(Wa[e], vw[2 * e + kc], s);
    qw[t] = vw[t] - EPS * s;
  }

  // assemble my 16 columns (overlaps waves 0,1's q-matvec)
  float rowq[16];
  const float* Wi = Wl + myi * WPAD;
  const float* Wj = Wl + myj * WPAD;
#pragma unroll
  for (int q = 0; q < 16; ++q) {
    int c = 16 * (q >> 2) + 4 * w + (q & 3);   // runtime-uniform (SGPR)
    int ic = __builtin_amdgcn_readlane(myi, c);
    int jc = __builtin_amdgcn_readlane(myj, c);
    float wcx = readlane_f(wx, c);
    float wcy = readlane_f(wy, c);
    float kap = (Wi[ic] - Wi[jc]) - (Wj[ic] - Wj[jc]);
    float aa = (wx * wcx + wy * wcy) * kap;
    aa = (c == lane) ? aa - ((lane < 32) ? EPS : 0.5f * EPS) : aa;
    rowq[q] = aa;
  }

  __syncthreads();                       // #2: qw visible

  // rhs (computed identically by all 4 waves)
  float rhs;
  {
    float qdx = qw[2 * myj]     - qw[2 * myi];
    float qdy = qw[2 * myj + 1] - qw[2 * myi + 1];
    float h = 0.0f;
    if (lane < 32) {
      float vdx = vw[2 * myj]     - vw[2 * myi];
      float vdy = vw[2 * myj + 1] - vw[2 * myi + 1];
      float jcnv = enx * vdx + eny * vdy;
      h = fminf(dist[b * NC + rc] * 12.5f, cor[b * NC + rc] * jcnv);
    }
    rhs = h - (wx * qdx + wy * qdy);
  }

  // Gauss-Jordan, no pivoting (S = PSD - eps*diag, diag >= ~2; round-1 notes)
  // 16 phases x 4 pivots; one barrier per phase.
#pragma unroll
  for (int g = 0; g < 16; ++g) {
    const int om = g & 3;                // owner wave (compile-time)
    const int gc = g >> 2;               // owner's local chunk
    float m0, m1, m2, m3;
    if (w == om) {                       // wave-uniform branch
      const int base = 4 * gc;
      {  // pivot 4g+0
        const int k = 4 * g;
        float r = rcp_fast(readlane_f(rowq[base], k));
        if (lane == k) dv[k] = r;
        m0 = (lane == k) ? 0.f : rowq[base] * r;
        rowq[base+1] = fmaf(-m0, readlane_f(rowq[base+1], k), rowq[base+1]);
        rowq[base+2] = fmaf(-m0, readlane_f(rowq[base+2], k), rowq[base+2]);
        rowq[base+3] = fmaf(-m0, readlane_f(rowq[base+3], k), rowq[base+3]);
      }
      {  // pivot 4g+1
        const int k = 4 * g + 1;
        float r = rcp_fast(readlane_f(rowq[base+1], k));
        if (lane == k) dv[k] = r;
        m1 = (lane == k) ? 0.f : rowq[base+1] * r;
        rowq[base+2] = fmaf(-m1, readlane_f(rowq[base+2], k), rowq[base+2]);
        rowq[base+3] = fmaf(-m1, readlane_f(rowq[base+3], k), rowq[base+3]);
      }
      {  // pivot 4g+2
        const int k = 4 * g + 2;
        float r = rcp_fast(readlane_f(rowq[base+2], k));
        if (lane == k) dv[k] = r;
        m2 = (lane == k) ? 0.f : rowq[base+2] * r;
        rowq[base+3] = fmaf(-m2, readlane_f(rowq[base+3], k), rowq[base+3]);
      }
      {  // pivot 4g+3
        const int k = 4 * g + 3;
        float r = rcp_fast(readlane_f(rowq[base+3], k));
        if (lane == k) dv[k] = r;
        m3 = (lane == k) ? 0.f : rowq[base+3] * r;
      }
      mrow[g & 1][lane] = make_float4(m0, m1, m2, m3);
    }
    __syncthreads();                     // m-vector (+dv) published
    if (w != om) {
      float4 mv = mrow[g & 1][lane];
      m0 = mv.x; m1 = mv.y; m2 = mv.z; m3 = mv.w;
    }
    // rhs: 4 sequential eliminations (lane 4g+s updated before broadcast s)
    rhs = fmaf(-m0, readlane_f(rhs, 4 * g),     rhs);
    rhs = fmaf(-m1, readlane_f(rhs, 4 * g + 1), rhs);
    rhs = fmaf(-m2, readlane_f(rhs, 4 * g + 2), rhs);
    rhs = fmaf(-m3, readlane_f(rhs, 4 * g + 3), rhs);
    // apply to my remaining columns (c > 4g+3)
#pragma unroll
    for (int cl = 0; cl < 4; ++cl) {
      if (cl < gc) continue;                       // compile-time prune
      if ((cl > gc) || (w > om)) {                 // uniform scalar guard
#pragma unroll
        for (int within = 0; within < 4; ++within) {
          const int q = 4 * cl + within;
          rowq[q] = fmaf(-m0, readlane_f(rowq[q], 4 * g),     rowq[q]);
          rowq[q] = fmaf(-m1, readlane_f(rowq[q], 4 * g + 1), rowq[q]);
          rowq[q] = fmaf(-m2, readlane_f(rowq[q], 4 * g + 2), rowq[q]);
          rowq[q] = fmaf(-m3, readlane_f(rowq[q], 4 * g + 3), rowq[q]);
        }
      }
    }
  }

  if (w >= 2) return;   // waves 2,3 done (HW decrements barrier wave count)

  // solution, lane-distributed (dv fully written before phase barriers)
  float myx = rhs * dv[lane];

  // y = G^T l, component half per wave (i in [0,32), j in [32,64))
  {
    float y = 0.f;
#pragma unroll
    for (int c = 0; c < NC; ++c) {
      float ex = readlane_f(wx, c),      ey = readlane_f(wy, c);       // en
      float tx = readlane_f(wx, c + 32), ty = readlane_f(wy, c + 32);  // et
      float lam = readlane_f(myx, c);
      float del = readlane_f(myx, c + 32);
      float wk = (kc ? ey : ex) * lam + (kc ? ty : tx) * del;
      if (w == 0) {
        int ic = __builtin_amdgcn_readlane(myi, c);
        y -= (ic == a) ? wk : 0.0f;
      } else {
        int jc = __builtin_amdgcn_readlane(myj, c);
        y += (jc == a) ? wk : 0.0f;
      }
    }
    yw[t] = y;
  }
  __syncthreads();                       // #3: yw visible (waves 0,1 alive)

  // v_plus = q + kron(W,I2) y ; out = [x passthrough, v_plus], half per wave
  {
    float s = 0.f;
    for (int e = 0; e < NBODY; ++e) s = fmaf(Wa[e], yw[2 * e + kc], s);
    float* ob = out + b * 256;
    ob[t]       = xb[t];
    ob[128 + t] = qw[t] + s;
  }
}

extern "C" void kernel_launch(void* const* d_in, const int* in_sizes, int n_in,
                              void* d_out, int out_size, void* d_ws, size_t ws_size,
                              hipStream_t stream) {
  const float* x    = (const float*)d_in[0];
  const float* v    = (const float*)d_in[1];
  const int*   cld  = (const int*)  d_in[2];
  const float* dist = (const float*)d_in[3];
  // d_in[4] = mu: drops out of the output (eliminated multipliers only)
  const float* cor  = (const float*)d_in[5];
  const float* Minv = (const float*)d_in[6];
  float* out = (float*)d_out;

  const int bs = in_sizes[0] / ND;          // 1024
  float* W = (float*)d_ws;                  // 64*64*4 = 16 KB scratch
  unsigned* flags = (unsigned*)((char*)d_ws + NBODY * NBODY * sizeof(float));

  solve_batch_fused<<<bs, 256, 0, stream>>>(x, v, cld, dist, cor, Minv, W,
                                            flags, out);
}

// Round 2
// 92.515 us; speedup vs baseline: 2.0478x; 2.0478x over previous
//
#include <hip/hip_runtime.h>
#include <math.h>

// ImpulseSolverLCP — round 8: revert to 2-dispatch (round-6 structure) +
// 8-phase x 8-pivot Gauss-Jordan (barriers 19 -> 10).
//
// Round-7 post-mortem: fused single-kernel with cross-block flag handshake
// stalled ~115us (agent-scope spin across non-coherent per-XCD L2s — flag
// line served stale from local L2 until eviction). Cross-block
// producer->consumer is ~100us on this part, not ~1us. Reverted.
//
// Math (identical to rounds 1-6, all PASSING):
//   K = [[pM+eI, G^T],[G, -F+eI]], pM = kron(M, I2), M = Minv^-1.
//   (pM+eI)^-1 = kron(W, I2), W = (I + e*Minv)^-1 Minv  (batch-shared).
//   Pair/row elimination leaves a symmetric 64x64 system in (lambda, delta):
//     A[r][c] = (w_r . w_c) * kap(r,c) - diag(e..e, e/2..e/2)
//   rhs_r = (r normal ? min(dist*12.5, cor*Jcnv) : 0) - w_r.(q_j - q_i)
//   q = v - e*kron(W,I2) v ;  v_plus = q + kron(W,I2) y ; y = scatter(G^T l).
//
// Round-8 change (why): 19 __syncthreads per block, each a full
// vmcnt/lgkmcnt drain + 4-wave rendezvous, on a solve whose VALU-issue floor
// is ~4.3us. Now:
//  * Columns owned in interleaved 8-col chunks: wave w owns global chunks
//    h in {w, w+4} (h=c>>3); local col q -> c = 32*(q>>3) + 8*w + (q&7).
//  * 8 phases of 8 pivots: owner does 8 SERIAL pivots in its own chunk
//    (static reg indices), publishes two float4 m-vectors per lane in
//    parity-double-buffered LDS slots; ONE barrier per phase (16+ -> 8).
//    The fma sequence per (row,col) is IDENTICAL to the 16x4 version (the
//    old inter-phase barrier only separated m0..m3 from m4..m7; same m
//    values, same order) -> bitwise-identical solution, absmax 0.02441406.
//  * Barrier #2 (qw visibility) folded into phase-0's publish barrier:
//    qw stores happen before any wave reaches that barrier; rhs assembly
//    (which reads qw cross-lane) moved to after it. Barriers: 1 staging +
//    8 phases + 1 yw = 10.
//  * Buffer safety: phase g readers of mrow[g&1] finish before barrier g+1;
//    the next writer of parity g&1 (phase g+2's owner) writes after
//    barrier g+1 — same argument as round 6.
//  * rhs maintained redundantly (bitwise-identically) by all 4 waves;
//    waves 2,3 s_endpgm after phase 7 (HW decrements barrier wave count);
//    waves 0,1 do the y-scatter + final matvec halves.

#define NBODY 64
#define NC    32
#define ND    128
#define EPS   1e-3f
#define WPAD  65

__device__ __forceinline__ float readlane_f(float x, int lane) {
  return __int_as_float(__builtin_amdgcn_readlane(__float_as_int(x), lane));
}

__device__ __forceinline__ float rcp_fast(float x) {
  float r;
  asm("v_rcp_f32 %0, %1" : "=v"(r) : "v"(x));
  return r;
}

// ---------------- Kernel 1: W = (I + eps*Minv)^-1 * Minv, Neumann ----------
__global__ __launch_bounds__(64) void precompute_W(
    const float* __restrict__ Minv, float* __restrict__ Wg) {
  const int lane = threadIdx.x;
  const int col = blockIdx.x;

  float Mr[NBODY];
  const float4* mv = (const float4*)(Minv + lane * NBODY);
#pragma unroll
  for (int e4 = 0; e4 < 16; ++e4) {
    float4 t = mv[e4];
    Mr[4 * e4] = t.x; Mr[4 * e4 + 1] = t.y;
    Mr[4 * e4 + 2] = t.z; Mr[4 * e4 + 3] = t.w;
  }

  const float dlt = (lane == col) ? 1.0f : 0.0f;
  float s = dlt;
#pragma unroll
  for (int t = 0; t < 6; ++t) {
    float a0 = 0.f, a1 = 0.f, a2 = 0.f, a3 = 0.f;
#pragma unroll
    for (int e = 0; e < NBODY; e += 4) {
      a0 = fmaf(Mr[e],     readlane_f(s, e),     a0);
      a1 = fmaf(Mr[e + 1], readlane_f(s, e + 1), a1);
      a2 = fmaf(Mr[e + 2], readlane_f(s, e + 2), a2);
      a3 = fmaf(Mr[e + 3], readlane_f(s, e + 3), a3);
    }
    s = dlt - EPS * ((a0 + a1) + (a2 + a3));
  }
  float a0 = 0.f, a1 = 0.f, a2 = 0.f, a3 = 0.f;
#pragma unroll
  for (int e = 0; e < NBODY; e += 4) {
    a0 = fmaf(Mr[e],     readlane_f(s, e),     a0);
    a1 = fmaf(Mr[e + 1], readlane_f(s, e + 1), a1);
    a2 = fmaf(Mr[e + 2], readlane_f(s, e + 2), a2);
    a3 = fmaf(Mr[e + 3], readlane_f(s, e + 3), a3);
  }
  Wg[lane * NBODY + col] = (a0 + a1) + (a2 + a3);
}

// ---------------- Kernel 2: 4-wave-per-batch Gauss-Jordan solve -------------
__global__ __launch_bounds__(256, 4) void solve_batch(
    const float* __restrict__ x, const float* __restrict__ v,
    const int* __restrict__ cld, const float* __restrict__ dist,
    const float* __restrict__ cor, const float* __restrict__ Wg,
    float* __restrict__ out) {
  __shared__ float Wl[NBODY * WPAD];
  __shared__ float vw[ND], qw[ND], yw[ND];
  __shared__ float4 mrowA[2][64];    // [phase parity][lane] = (m0,m1,m2,m3)
  __shared__ float4 mrowB[2][64];    // [phase parity][lane] = (m4,m5,m6,m7)
  __shared__ float dv[64];           // pivot reciprocals

  const int tid  = threadIdx.x;
  const int w    = tid >> 6;         // wave id 0..3 (uniform per wave)
  const int lane = tid & 63;
  const int b    = blockIdx.x;

  for (int idx = tid; idx < NBODY * NBODY; idx += 256)
    Wl[(idx >> 6) * WPAD + (idx & 63)] = Wg[idx];

  const float* xb = x + b * ND;
  const float* vb = v + b * ND;

  const int half = w & 1;
  const int t = lane + 64 * half;    // output component (waves 0,1)
  if (w < 2) vw[t] = vb[t];

  // per-lane contact/row data (identical in all 4 waves)
  const int rc = lane & 31;
  const int myi = cld[b * 2 * NC + 2 * rc];
  const int myj = cld[b * 2 * NC + 2 * rc + 1];
  float dx = xb[2 * myj]     - xb[2 * myi];
  float dy = xb[2 * myj + 1] - xb[2 * myi + 1];
  float il = 1.0f / sqrtf(dx * dx + dy * dy);
  float enx = dx * il, eny = dy * il;
  float wx = (lane < 32) ? enx : -eny;   // row weight vector (en or et)
  float wy = (lane < 32) ? eny : enx;

  __syncthreads();                       // #1: Wl + vw visible

  const int kc = lane & 1;
  const int a  = t >> 1;
  const float* Wa = Wl + a * WPAD;
  float qreg = 0.f;
  if (w < 2) {                           // q = v - eps*kron(W,I2) v, half each
    float s = 0.f;
    for (int e = 0; e < NBODY; ++e) s = fmaf(Wa[e], vw[2 * e + kc], s);
    qreg = vw[t] - EPS * s;
    qw[t] = qreg;
  }

  // h-part of rhs (vw-dependent only; vw synced by barrier #1)
  float hterm = 0.0f;
  if (lane < 32) {
    float vdx = vw[2 * myj]     - vw[2 * myi];
    float vdy = vw[2 * myj + 1] - vw[2 * myi + 1];
    float jcnv = enx * vdx + eny * vdy;
    hterm = fminf(dist[b * NC + rc] * 12.5f, cor[b * NC + rc] * jcnv);
  }

  // assemble my 16 columns (overlaps waves 0,1's q-matvec)
  float rowq[16];
  const float* Wi = Wl + myi * WPAD;
  const float* Wj = Wl + myj * WPAD;
#pragma unroll
  for (int q = 0; q < 16; ++q) {
    int c = 32 * (q >> 3) + 8 * w + (q & 7);   // runtime-uniform (SGPR)
    int ic = __builtin_amdgcn_readlane(myi, c);
    int jc = __builtin_amdgcn_readlane(myj, c);
    float wcx = readlane_f(wx, c);
    float wcy = readlane_f(wy, c);
    float kap = (Wi[ic] - Wi[jc]) - (Wj[ic] - Wj[jc]);
    float aa = (wx * wcx + wy * wcy) * kap;
    aa = (c == lane) ? aa - ((lane < 32) ? EPS : 0.5f * EPS) : aa;
    rowq[q] = aa;
  }

  // Gauss-Jordan, no pivoting (S = PSD - eps*diag, diag >= ~2; round-1 notes)
  // 8 phases x 8 pivots; one barrier per phase. qw-visibility rides on the
  // phase-0 barrier (all qw stores are in program order before it).
  float rhs = 0.0f;
#pragma unroll
  for (int g = 0; g < 8; ++g) {
    const int om = g & 3;                // owner wave (compile-time)
    const int gc = g >> 2;               // owner's local chunk (0 or 1)
    float m[8];
    if (w == om) {                       // wave-uniform branch
      const int base = 8 * gc;
#pragma unroll
      for (int s = 0; s < 8; ++s) {      // 8 serial pivots, static indices
        const int k = 8 * g + s;
        float r = rcp_fast(readlane_f(rowq[base + s], k));
        if (lane == k) dv[k] = r;
        m[s] = (lane == k) ? 0.f : rowq[base + s] * r;
#pragma unroll
        for (int u = s + 1; u < 8; ++u)
          rowq[base + u] = fmaf(-m[s], readlane_f(rowq[base + u], k),
                                rowq[base + u]);
      }
      mrowA[g & 1][lane] = make_float4(m[0], m[1], m[2], m[3]);
      mrowB[g & 1][lane] = make_float4(m[4], m[5], m[6], m[7]);
    }
    __syncthreads();                     // m-vector (+dv) published
    if (g == 0) {                        // rhs assembly (reads qw cross-lane)
      float qdx = qw[2 * myj]     - qw[2 * myi];
      float qdy = qw[2 * myj + 1] - qw[2 * myi + 1];
      rhs = hterm - (wx * qdx + wy * qdy);
    }
    if (w != om) {
      float4 ma = mrowA[g & 1][lane];
      float4 mb = mrowB[g & 1][lane];
      m[0] = ma.x; m[1] = ma.y; m[2] = ma.z; m[3] = ma.w;
      m[4] = mb.x; m[5] = mb.y; m[6] = mb.z; m[7] = mb.w;
    }
    // rhs: 8 sequential eliminations (lane 8g+s updated before broadcast s)
#pragma unroll
    for (int s = 0; s < 8; ++s)
      rhs = fmaf(-m[s], readlane_f(rhs, 8 * g + s), rhs);
    // apply to my remaining columns (c > 8g+7)
#pragma unroll
    for (int cl = 0; cl < 2; ++cl) {
      if (cl < gc) continue;                       // compile-time prune
      if ((cl > gc) || (w > om)) {                 // uniform scalar guard
#pragma unroll
        for (int within = 0; within < 8; ++within) {
          const int q = 8 * cl + within;
#pragma unroll
          for (int s = 0; s < 8; ++s)
            rowq[q] = fmaf(-m[s], readlane_f(rowq[q], 8 * g + s), rowq[q]);
        }
      }
    }
  }

  if (w >= 2) return;   // waves 2,3 done (HW decrements barrier wave count)

  // solution, lane-distributed (dv fully written before phase barriers)
  float myx = rhs * dv[lane];

  // y = G^T l, component half per wave (i in [0,32), j in [32,64))
  {
    float y = 0.f;
#pragma unroll
    for (int c = 0; c < NC; ++c) {
      float ex = readlane_f(wx, c),      ey = readlane_f(wy, c);       // en
      float tx = readlane_f(wx, c + 32), ty = readlane_f(wy, c + 32);  // et
      float lam = readlane_f(myx, c);
      float del = readlane_f(myx, c + 32);
      float wk = (kc ? ey : ex) * lam + (kc ? ty : tx) * del;
      if (w == 0) {
        int ic = __builtin_amdgcn_readlane(myi, c);
        y -= (ic == a) ? wk : 0.0f;
      } else {
        int jc = __builtin_amdgcn_readlane(myj, c);
        y += (jc == a) ? wk : 0.0f;
      }
    }
    yw[t] = y;
  }
  __syncthreads();                       // #3: yw visible (waves 0,1 alive)

  // v_plus = q + kron(W,I2) y ; out = [x passthrough, v_plus], half per wave
  {
    float s = 0.f;
    for (int e = 0; e < NBODY; ++e) s = fmaf(Wa[e], yw[2 * e + kc], s);
    float* ob = out + b * 256;
    ob[t]       = xb[t];
    ob[128 + t] = qreg + s;
  }
}

extern "C" void kernel_launch(void* const* d_in, const int* in_sizes, int n_in,
                              void* d_out, int out_size, void* d_ws, size_t ws_size,
                              hipStream_t stream) {
  const float* x    = (const float*)d_in[0];
  const float* v    = (const float*)d_in[1];
  const int*   cld  = (const int*)  d_in[2];
  const float* dist = (const float*)d_in[3];
  // d_in[4] = mu: drops out of the output (eliminated multipliers only)
  const float* cor  = (const float*)d_in[5];
  const float* Minv = (const float*)d_in[6];
  float* out = (float*)d_out;

  const int bs = in_sizes[0] / ND;          // 1024
  float* W = (float*)d_ws;                  // 64*64*4 = 16 KB scratch

  precompute_W<<<NBODY, 64, 0, stream>>>(Minv, W);
  solve_batch<<<bs, 256, 0, stream>>>(x, v, cld, dist, cor, W, out);
}